// Round 8
// baseline (45.159 us; speedup 1.0000x reference)
//
#include <hip/hip_runtime.h>

// RandomShift (DrQ-style): x[512,9,84,84] f32, shift[512,2] int32 in [0,8].
// out[n,c,i,j] = bilinear tap of zero-padded x at
// (row = j*91/83 + s1 - 4, col = i*91/83 + s0 - 4), image coords in [0,84).
//
// v7 = v6 with exactly ONE change: plain float4 stores (nontemporal hint
// removed) to A/B the HBM write-path aggregation theory.
//  - 3 planes per block (shared shift -> params hoisted once per block)
//  - double-buffered LDS; next plane's global loads issued before compute
//    (T14 async-split), ds_write after, one barrier per plane.

constexpr int HW     = 84;
constexpr int LDSW   = 85;           // gcd(85,32)=1
constexpr int NPLANE = HW * HW;      // 7056
constexpr int NQUADS = NPLANE / 4;   // 1764 = 3*512 + 228

typedef float vfloat4 __attribute__((ext_vector_type(4)));

__device__ __forceinline__ int iclamp(int v, int lo, int hi) {
    return v < lo ? lo : (v > hi ? hi : v);
}

__global__ __launch_bounds__(512) void rshift_kernel(
    const float* __restrict__ x,
    const int*   __restrict__ shift,
    float*       __restrict__ out)
{
    __shared__ float lds[2][HW * LDSW];

    const int blk = blockIdx.x;            // 0..1535
    const int n   = blk / 3;
    const int c0  = (blk - n * 3) * 3;     // planes c0..c0+2 of image n
    const float s0 = (float)shift[2 * n];      // along i (columns)
    const float s1 = (float)shift[2 * n + 1];  // along j (rows)
    const float R  = 91.0f / 83.0f;
    const int t    = threadIdx.x;

    const size_t pbase = ((size_t)n * 9 + c0) * NPLANE;
    const float* __restrict__ src = x   + pbase;
    float*       __restrict__ dst = out + pbase;

    const int lane = t & 63;
    const int wv   = t >> 6;               // 0..7
    const int jq   = lane % 21;
    const int isub = lane / 21;            // 0..2 active, 3 idle

    // ---- hoisted y-params (slot-weight form) ----
    float wy0s[4], wy1s[4];
    int   rr[4];
    #pragma unroll
    for (int e = 0; e < 4; ++e) {
        float fy = fmaf((float)(4 * jq + e), R, s1);
        int   y0 = (int)fy;
        float w1 = fy - (float)y0;
        float w0 = 1.0f - w1;
        int   t0 = y0 - 4;
        int   cb = iclamp(t0, 0, HW - 2);
        wy0s[e] = (t0 == cb) ? w0 : ((t0 + 1 == cb) ? w1 : 0.0f);
        wy1s[e] = (t0 == cb) ? w1 : ((t0 - 1 == cb) ? w0 : 0.0f);
        rr[e] = cb;
    }

    // ---- hoisted x-params per sweep k (i = k*24 + wv*3 + isub) ----
    float wx0h[4], wx1h[4];
    int   cu0h[4];
    bool  iok[4];
    #pragma unroll
    for (int k = 0; k < 4; ++k) {
        int i  = k * 24 + wv * 3 + isub;
        iok[k] = (isub < 3) && (i < HW);
        float fx = fmaf((float)i, R, s0);
        int   x0 = (int)fx;
        float w1 = fx - (float)x0;
        float w0 = 1.0f - w1;
        int   u0 = x0 - 4;
        int   cb = iclamp(u0, 0, HW - 2);
        wx0h[k] = (u0 == cb) ? w0 : ((u0 + 1 == cb) ? w1 : 0.0f);
        wx1h[k] = (u0 == cb) ? w1 : ((u0 - 1 == cb) ? w0 : 0.0f);
        cu0h[k] = cb * LDSW;
    }

    // ---- staging helpers (quads q = t, t+512, t+1024, t+1536) ----
    auto loadp = [&](int p, vfloat4& a0, vfloat4& a1, vfloat4& a2, vfloat4& a3) {
        const float* s = src + (size_t)p * NPLANE;
        a0 = *reinterpret_cast<const vfloat4*>(s + 4 * t);
        a1 = *reinterpret_cast<const vfloat4*>(s + 4 * (t + 512));
        a2 = *reinterpret_cast<const vfloat4*>(s + 4 * (t + 1024));
        if (t < NQUADS - 1536)
            a3 = *reinterpret_cast<const vfloat4*>(s + 4 * (t + 1536));
    };
    auto put1 = [&](float* buf, int q, vfloat4 v) {
        int row  = q / 21;
        int col0 = (q - row * 21) * 4;
        int b    = col0 * LDSW + row;
        buf[b]            = v.x;
        buf[b + LDSW]     = v.y;
        buf[b + 2 * LDSW] = v.z;
        buf[b + 3 * LDSW] = v.w;
    };
    auto writep = [&](float* buf, vfloat4 a0, vfloat4 a1, vfloat4 a2, vfloat4 a3) {
        put1(buf, t,        a0);
        put1(buf, t + 512,  a1);
        put1(buf, t + 1024, a2);
        if (t < NQUADS - 1536) put1(buf, t + 1536, a3);
    };
    auto computep = [&](int p, const float* buf) {
        float* d = dst + (size_t)p * NPLANE;
        #pragma unroll
        for (int k = 0; k < 4; ++k) {
            if (iok[k]) {
                int i = k * 24 + wv * 3 + isub;
                vfloat4 o;
                #pragma unroll
                for (int e = 0; e < 4; ++e) {
                    int   b0 = cu0h[k] + rr[e];       // col cb,   rows rr,rr+1
                    int   b1 = b0 + LDSW;             // col cb+1
                    o[e] = wx0h[k] * fmaf(wy0s[e], buf[b0], wy1s[e] * buf[b0 + 1])
                         + wx1h[k] * fmaf(wy0s[e], buf[b1], wy1s[e] * buf[b1 + 1]);
                }
                *reinterpret_cast<vfloat4*>(d + (size_t)i * HW + 4 * jq) = o;
            }
        }
    };

    // ---- pipeline: stage 0; {load p+1 | compute p | write p+1 | barrier} ----
    vfloat4 a0, a1, a2, a3;
    loadp(0, a0, a1, a2, a3);
    writep(&lds[0][0], a0, a1, a2, a3);
    __syncthreads();

    #pragma unroll
    for (int p = 0; p < 3; ++p) {
        vfloat4 b0, b1, b2, b3;
        if (p < 2) loadp(p + 1, b0, b1, b2, b3);   // in flight under compute
        computep(p, &lds[p & 1][0]);
        if (p < 2) {
            writep(&lds[(p + 1) & 1][0], b0, b1, b2, b3);
            __syncthreads();
        }
    }
}

extern "C" void kernel_launch(void* const* d_in, const int* in_sizes, int n_in,
                              void* d_out, int out_size, void* d_ws, size_t ws_size,
                              hipStream_t stream) {
    const float* x     = (const float*)d_in[0];
    const int*   shift = (const int*)d_in[1];
    float*       out   = (float*)d_out;
    const int blocks = 512 * 3;        // 3 planes per block
    rshift_kernel<<<blocks, 512, 0, stream>>>(x, shift, out);
}

// Round 9
// 44.948 us; speedup vs baseline: 1.0047x; 1.0047x over previous
//
#include <hip/hip_runtime.h>

// RandomShift (DrQ-style): x[512,9,84,84] f32, shift[512,2] int32 in [0,8].
// out[n,c,i,j] = bilinear tap of zero-padded x at
// (row = j*91/83 + s1 - 4, col = i*91/83 + s0 - 4), image coords in [0,84).
//
// v8 = v6 internals, persistent-style scheduling: ONE block per image n
// (grid 512 = exactly 2 blocks/CU, single generation, uniform work), each
// block loops all 9 planes (same shift -> all interp params hoisted once).
// Rotation per plane: {issue plane p+1 global loads | compute plane p |
// ds_write p+1 | barrier} -> steady-state pipeline for 8 of 9 planes.

constexpr int HW     = 84;
constexpr int LDSW   = 85;           // gcd(85,32)=1
constexpr int NPLANE = HW * HW;      // 7056
constexpr int NQUADS = NPLANE / 4;   // 1764 = 3*512 + 228

typedef float vfloat4 __attribute__((ext_vector_type(4)));

__device__ __forceinline__ int iclamp(int v, int lo, int hi) {
    return v < lo ? lo : (v > hi ? hi : v);
}

__global__ __launch_bounds__(512) void rshift_kernel(
    const float* __restrict__ x,
    const int*   __restrict__ shift,
    float*       __restrict__ out)
{
    __shared__ float lds[2][HW * LDSW];

    const int n    = blockIdx.x;           // one block per image
    const float s0 = (float)shift[2 * n];      // along i (columns)
    const float s1 = (float)shift[2 * n + 1];  // along j (rows)
    const float R  = 91.0f / 83.0f;
    const int t    = threadIdx.x;

    const size_t pbase = (size_t)n * 9 * NPLANE;
    const float* __restrict__ src = x   + pbase;
    float*       __restrict__ dst = out + pbase;

    const int lane = t & 63;
    const int wv   = t >> 6;               // 0..7
    const int jq   = lane % 21;
    const int isub = lane / 21;            // 0..2 active, 3 idle

    // ---- hoisted y-params (slot-weight form), once per 9 planes ----
    float wy0s[4], wy1s[4];
    int   rr[4];
    #pragma unroll
    for (int e = 0; e < 4; ++e) {
        float fy = fmaf((float)(4 * jq + e), R, s1);
        int   y0 = (int)fy;
        float w1 = fy - (float)y0;
        float w0 = 1.0f - w1;
        int   t0 = y0 - 4;
        int   cb = iclamp(t0, 0, HW - 2);
        wy0s[e] = (t0 == cb) ? w0 : ((t0 + 1 == cb) ? w1 : 0.0f);
        wy1s[e] = (t0 == cb) ? w1 : ((t0 - 1 == cb) ? w0 : 0.0f);
        rr[e] = cb;
    }

    // ---- hoisted x-params per sweep k (i = k*24 + wv*3 + isub) ----
    float wx0h[4], wx1h[4];
    int   cu0h[4];
    bool  iok[4];
    #pragma unroll
    for (int k = 0; k < 4; ++k) {
        int i  = k * 24 + wv * 3 + isub;
        iok[k] = (isub < 3) && (i < HW);
        float fx = fmaf((float)i, R, s0);
        int   x0 = (int)fx;
        float w1 = fx - (float)x0;
        float w0 = 1.0f - w1;
        int   u0 = x0 - 4;
        int   cb = iclamp(u0, 0, HW - 2);
        wx0h[k] = (u0 == cb) ? w0 : ((u0 + 1 == cb) ? w1 : 0.0f);
        wx1h[k] = (u0 == cb) ? w1 : ((u0 - 1 == cb) ? w0 : 0.0f);
        cu0h[k] = cb * LDSW;
    }

    // ---- staging helpers (quads q = t, t+512, t+1024, t+1536) ----
    auto loadp = [&](int p, vfloat4& a0, vfloat4& a1, vfloat4& a2, vfloat4& a3) {
        const float* s = src + (size_t)p * NPLANE;
        a0 = *reinterpret_cast<const vfloat4*>(s + 4 * t);
        a1 = *reinterpret_cast<const vfloat4*>(s + 4 * (t + 512));
        a2 = *reinterpret_cast<const vfloat4*>(s + 4 * (t + 1024));
        if (t < NQUADS - 1536)
            a3 = *reinterpret_cast<const vfloat4*>(s + 4 * (t + 1536));
    };
    auto put1 = [&](float* buf, int q, vfloat4 v) {
        int row  = q / 21;
        int col0 = (q - row * 21) * 4;
        int b    = col0 * LDSW + row;
        buf[b]            = v.x;
        buf[b + LDSW]     = v.y;
        buf[b + 2 * LDSW] = v.z;
        buf[b + 3 * LDSW] = v.w;
    };
    auto writep = [&](float* buf, vfloat4 a0, vfloat4 a1, vfloat4 a2, vfloat4 a3) {
        put1(buf, t,        a0);
        put1(buf, t + 512,  a1);
        put1(buf, t + 1024, a2);
        if (t < NQUADS - 1536) put1(buf, t + 1536, a3);
    };
    auto computep = [&](int p, const float* buf) {
        float* d = dst + (size_t)p * NPLANE;
        #pragma unroll
        for (int k = 0; k < 4; ++k) {
            if (iok[k]) {
                int i = k * 24 + wv * 3 + isub;
                vfloat4 o;
                #pragma unroll
                for (int e = 0; e < 4; ++e) {
                    int   b0 = cu0h[k] + rr[e];       // col cb,   rows rr,rr+1
                    int   b1 = b0 + LDSW;             // col cb+1
                    o[e] = wx0h[k] * fmaf(wy0s[e], buf[b0], wy1s[e] * buf[b0 + 1])
                         + wx1h[k] * fmaf(wy0s[e], buf[b1], wy1s[e] * buf[b1 + 1]);
                }
                __builtin_nontemporal_store(
                    o, reinterpret_cast<vfloat4*>(d + (size_t)i * HW + 4 * jq));
            }
        }
    };

    // ---- pipeline over 9 planes: steady state for 8 of them ----
    vfloat4 a0, a1, a2, a3;
    loadp(0, a0, a1, a2, a3);
    writep(&lds[0][0], a0, a1, a2, a3);
    __syncthreads();

    for (int p = 0; p < 9; ++p) {
        vfloat4 b0, b1, b2, b3;
        if (p < 8) loadp(p + 1, b0, b1, b2, b3);   // in flight under compute
        computep(p, &lds[p & 1][0]);
        if (p < 8) {
            writep(&lds[(p + 1) & 1][0], b0, b1, b2, b3);
            __syncthreads();
        }
    }
}

extern "C" void kernel_launch(void* const* d_in, const int* in_sizes, int n_in,
                              void* d_out, int out_size, void* d_ws, size_t ws_size,
                              hipStream_t stream) {
    const float* x     = (const float*)d_in[0];
    const int*   shift = (const int*)d_in[1];
    float*       out   = (float*)d_out;
    rshift_kernel<<<512, 512, 0, stream>>>(x, shift, out);   // 1 block per n
}